// Round 6
// baseline (244.555 us; speedup 1.0000x reference)
//
#include <hip/hip_runtime.h>
#include <hip/hip_cooperative_groups.h>
#include <cstdio>
#include <cstdint>

namespace cg = cooperative_groups;

static constexpr int  MPIX   = 51529;   // 227*227
static constexpr int  NBATCH = 8;
static constexpr int  NTH    = 256;     // number of thresholds
static constexpr int  HD     = 257;     // rank histogram dim (0..256)
static constexpr int  HP     = 260;     // padded H pitch (rows 16B-aligned)
static constexpr int  GRP    = 33;      // ceil(257/8) rank groups of 8
static constexpr int  BINCAP = 3968;    // records per (batch,group) bin
static constexpr int  NBLK   = 256;     // cooperative grid (1 block/CU guaranteed residency)
static constexpr int  NCHUNK = 512;     // matvec chunks (256 r x 2 s-halves)

// ws layout (float slots) — d_ws is 256 MiB
static constexpr long PSA_OFF   = 0;     // 256 floats (sorted phi_a)
static constexpr long IA_OFF    = 256;   // 256 ints
static constexpr long PSB_OFF   = 512;   // 256 floats
static constexpr long IB_OFF    = 768;   // 256 ints
static constexpr long CUR_OFF   = 1024;  // 264 ints (bin cursors)   [memset 0 each call]
static constexpr long MVC_OFF   = 1288;  // 1 int (completion ctr)   [memset 0 each call]
static constexpr long BASEA_OFF = 1312;  // 257 ints (LUT)
static constexpr long BASEB_OFF = 1600;  // 257 ints
static constexpr long H_OFF     = 2048;
static constexpr long H_SZ      = (long)NBATCH * HD * HP;        // 534560
static constexpr long GBC_OFF   = H_OFF + H_SZ;
static constexpr long GBC_SZ    = (long)NBATCH * NTH * NTH;      // 524288
static constexpr long BINS_OFF  = GBC_OFF + GBC_SZ;
static constexpr long BINS_SZ   = (long)NBATCH * GRP * BINCAP;   // 1047552
static constexpr long PART_OFF  = BINS_OFF + BINS_SZ;
static constexpr long PART_SZ   = (long)NCHUNK * 256;            // 131072
static constexpr long TOTAL_FLOATS = PART_OFF + PART_SZ;         // ~8.96 MB

__device__ __forceinline__ float clamp01(float v) {
    return fminf(fmaxf(v, 0.f), 1.f);
}

// LUT decode: c0 = first idx with lv[i] >= v ; c1 = first idx with lv[i] > v-1
__device__ __forceinline__ void decode_lut(const float* __restrict__ lv,
                                           const int* __restrict__ lbase,
                                           float v, int& c1, int& c0) {
    if (v <= 0.f) { c1 = 0; c0 = 0; return; }
    int j = min((int)v, 255);
    int i = lbase[j];
    while (i < 256 && lv[i] < v) ++i;
    c0 = i;
    float u = v - 1.f;
    if (u < 0.f) { c1 = 0; return; }
    int j1 = min((int)u, 255);
    int i1 = lbase[j1];
    while (i1 < 256 && lv[i1] <= u) ++i1;
    c1 = i1;
}

// per-phase LDS unions
struct P1S {  // sort + bin
    float raw[256];
    float la[256];  int lidx[256];
    float lb[256];  int lidxB[256];
    int   cnt4[256][4];
    int   lbaseA[257];
    int   lcnt[GRP], lbs[GRP];
};
struct P2S {  // accumulate + row scans
    float la[256], lb[256];
    int   lbA[257], lbB[257];
    float lHG[16][257];   // rows 0..7 = H, 8..15 = Gb
    float lT[16][257];
    float lGa[256][9];    // [s][ca1-r0], padded stride 9
    float lCsp[8][256];
};
struct P3S {  // column scans: 4 subgroups x (4 cols x 264 rows) x2
    float s0[4][4][264];
    float s1[4][4][264];
};
struct P4S {  // matvec
    float Wl[128][32];
    float gl[8][128];
    float qp[4][256];
    int   lastFlag;
};

static_assert(sizeof(P1S) <= sizeof(P2S), "");
static_assert(sizeof(P3S) <= sizeof(P2S), "");
static_assert(sizeof(P4S) <= sizeof(P2S), "");

__global__ void __launch_bounds__(1024)
k_mega(const float* __restrict__ x, const float* __restrict__ pa,
       const float* __restrict__ pb, const float* __restrict__ W,
       const float* __restrict__ bias, float* __restrict__ out,
       float* psa, int* ia, float* psb, int* ib, int* baseA, int* baseB,
       int* cursor, int* mvc, float* H, float* GbC, int* bins, float* partial) {
    cg::grid_group grid = cg::this_grid();
    __shared__ __align__(16) char smem[sizeof(P2S)];
    int t = threadIdx.x;

    //================ P1: local sort of phi_a (+LUT), binning; block 0 publishes ================
    {
        P1S& s = *reinterpret_cast<P1S*>(smem);
        if (t < 256) s.raw[t] = pa[t];
        if (t < GRP) s.lcnt[t] = 0;
        __syncthreads();
        {   // stable rank via 4-way split count
            int e = t & 255, q = t >> 8;
            float v = s.raw[e]; int c = 0;
            int j0 = q * 64;
            for (int j = j0; j < j0 + 64; ++j) {
                float w = s.raw[j];
                c += (w < v) || (w == v && j < e);
            }
            s.cnt4[e][q] = c;
        }
        __syncthreads();
        if (t < 256) {
            int r = s.cnt4[t][0] + s.cnt4[t][1] + s.cnt4[t][2] + s.cnt4[t][3];
            s.la[r] = s.raw[t];
            s.lidx[r] = t;
        }
        __syncthreads();
        if (t < 257) {
            float v = (float)t;
            int lo = 0, hi = 256;
            while (lo < hi) { int m = (lo + hi) >> 1; if (s.la[m] < v) lo = m + 1; else hi = m; }
            s.lbaseA[t] = lo;
        }
        __syncthreads();
        if (blockIdx.x == 0) {   // block-uniform: also sort B and publish all tables
            if (t < 256) s.raw[t] = pb[t];
            __syncthreads();
            {
                int e = t & 255, q = t >> 8;
                float v = s.raw[e]; int c = 0;
                int j0 = q * 64;
                for (int j = j0; j < j0 + 64; ++j) {
                    float w = s.raw[j];
                    c += (w < v) || (w == v && j < e);
                }
                s.cnt4[e][q] = c;
            }
            __syncthreads();
            if (t < 256) {
                int r = s.cnt4[t][0] + s.cnt4[t][1] + s.cnt4[t][2] + s.cnt4[t][3];
                s.lb[r] = s.raw[t];
                s.lidxB[r] = t;
            }
            __syncthreads();
            if (t < 256) { psa[t] = s.la[t]; ia[t] = s.lidx[t]; psb[t] = s.lb[t]; ib[t] = s.lidxB[t]; }
            if (t < 257) {
                baseA[t] = s.lbaseA[t];
                float v = (float)t;
                int lo = 0, hi = 256;
                while (lo < hi) { int m = (lo + hi) >> 1; if (s.lb[m] < v) lo = m + 1; else hi = m; }
                baseB[t] = lo;
            }
        }
        __syncthreads();

        // binning: 256 blocks = 8 batches x 32 pixel chunks; <=2 manual iterations/thread
        int b  = blockIdx.x >> 5;
        int ci = blockIdx.x & 31;
        const int CHUNK = (MPIX + 31) / 32;   // 1611
        int k0 = ci * CHUNK, k1 = min(k0 + CHUNK, MPIX);
        int kA = k0 + t, kB = k0 + t + 1024;
        int gA0 = 0, gA1 = -1, gB0 = 0, gB1 = -1;
        if (kA < k1) {
            float a = x[(long)b * MPIX + kA];
            int ca1, ca0; decode_lut(s.la, s.lbaseA, a, ca1, ca0);
            int wa = min(ca0 - ca1, 127);
            gA0 = ca1 >> 3; gA1 = (ca1 + max(wa, 1) - 1) >> 3;
            for (int g = gA0; g <= gA1; ++g) atomicAdd(&s.lcnt[g], 1);
        }
        if (kB < k1) {
            float a = x[(long)b * MPIX + kB];
            int ca1, ca0; decode_lut(s.la, s.lbaseA, a, ca1, ca0);
            int wa = min(ca0 - ca1, 127);
            gB0 = ca1 >> 3; gB1 = (ca1 + max(wa, 1) - 1) >> 3;
            for (int g = gB0; g <= gB1; ++g) atomicAdd(&s.lcnt[g], 1);
        }
        __syncthreads();
        if (t < GRP) { s.lbs[t] = atomicAdd(&cursor[b * GRP + t], s.lcnt[t]); s.lcnt[t] = 0; }
        __syncthreads();
        if (kA < k1) {
            for (int g = gA0; g <= gA1; ++g) {
                int r = atomicAdd(&s.lcnt[g], 1);
                int slot = s.lbs[g] + r;
                if (slot < BINCAP) bins[((long)b * GRP + g) * BINCAP + slot] = kA;
            }
        }
        if (kB < k1) {
            for (int g = gB0; g <= gB1; ++g) {
                int r = atomicAdd(&s.lcnt[g], 1);
                int slot = s.lbs[g] + r;
                if (slot < BINCAP) bins[((long)b * GRP + g) * BINCAP + slot] = kB;
            }
        }
    }
    grid.sync();

    //================ P2: per-(batch, 8-rank-group) LDS accumulation + row scans ================
    {
        P2S& s = *reinterpret_cast<P2S*>(smem);
        for (int i = t; i < 256; i += 1024) { s.la[i] = psa[i]; s.lb[i] = psb[i]; }
        for (int i = t; i < 257; i += 1024) { s.lbA[i] = baseA[i]; s.lbB[i] = baseB[i]; }
        for (int task = blockIdx.x; task < NBATCH * GRP; task += NBLK) {
            int b = task / GRP, g = task % GRP;
            int r0 = g * 8;
            int rlen = min(8, HD - r0);
            __syncthreads();   // prior task's flush reads done; table loads done (1st iter)
            for (int i = t; i < 16 * 257; i += 1024) (&s.lHG[0][0])[i] = 0.f;
            for (int i = t; i < 256 * 9; i += 1024) (&s.lGa[0][0])[i] = 0.f;
            for (int i = t; i < 8 * 256; i += 1024) (&s.lCsp[0][0])[i] = 0.f;
            __syncthreads();

            const long kb = (long)b * MPIX;
            int cnt = min(cursor[b * GRP + g], BINCAP);
            const int* mybin = bins + ((long)b * GRP + g) * BINCAP;
            for (int i = t; i < cnt; i += 1024) {
                int k = mybin[i];
                float a  = x[kb + k];
                float bd = a - ((k + 1 < MPIX) ? x[kb + k + 1] : 0.f);
                int ca1, ca0, cb1, cb0;
                decode_lut(s.la, s.lbA, a, ca1, ca0);
                decode_lut(s.lb, s.lbB, bd, cb1, cb0);
                int wa = min(ca0 - ca1, 127);
                int wb = min(cb0 - cb1, 127);
                int d = ca1 - r0;
                bool owna = (unsigned)d < (unsigned)rlen;
                int rlo = max(ca1, r0);
                int rhi = min(ca1 + wa, r0 + rlen);
                if (owna) {
                    atomicAdd(&s.lHG[d][cb1], 1.0f);
                    for (int ss = cb1; ss < cb1 + wb; ++ss)
                        atomicAdd(&s.lGa[ss][d], clamp01(bd - s.lb[ss]));
                }
                for (int r = rlo; r < rhi; ++r) {
                    float f = clamp01(a - s.la[r]);
                    int rr = r - r0;
                    atomicAdd(&s.lHG[8 + rr][cb1], f);
                    for (int ss = cb1; ss < cb1 + wb; ++ss)
                        atomicAdd(&s.lCsp[rr][ss], f * clamp01(bd - s.lb[ss]));
                }
            }
            __syncthreads();

            // combined suffix-scan of lHG rows along cb1 (9 passes)
            float* src = &s.lHG[0][0];
            float* dst = &s.lT[0][0];
            for (int dd = 1; dd < 257; dd <<= 1) {
                for (int i = t; i < 16 * 257; i += 1024) {
                    int c = i % 257;
                    dst[i] = src[i] + ((c + dd < 257) ? src[i + dd] : 0.f);
                }
                __syncthreads();
                float* tmp = src; src = dst; dst = tmp;
            }
            // flush GbC[r][s] = SufGb[r][s+1] + Csp[r][s]
            int rgb = max(0, min(rlen, NTH - r0));
            for (int rr = 0; rr < rgb; ++rr) {
                const float* gbS = src + (8 + rr) * 257;
                float* dstg = GbC + ((long)b * NTH + (r0 + rr)) * NTH;
                for (int ss = t; ss < 256; ss += 1024) dstg[ss] = gbS[ss + 1] + s.lCsp[rr][ss];
            }
            // flush H[p][q] = rowScanH[p][q] + lGa[q-1][p-r0]  (column scan finishes both)
            for (int rr = 0; rr < rlen; ++rr) {
                const float* hS = src + rr * 257;
                float* dsth = H + ((long)b * HD + (r0 + rr)) * HP;
                for (int q = t; q < 257; q += 1024)
                    dsth[q] = hS[q] + ((q >= 1) ? s.lGa[q - 1][rr] : 0.f);
            }
        }
    }
    grid.sync();

    //================ P3: column suffix scans of H along ca1 (4 col-quads per block) ================
    {
        P3S& s = *reinterpret_cast<P3S*>(smem);
        int sg = t >> 8;                     // subgroup 0..3
        int l256 = t & 255;
        int task = blockIdx.x * 4 + sg;      // 0..1023, active < 520
        bool act = task < NBATCH * 65;
        float (*s0)[264] = s.s0[sg];
        float (*s1p)[264] = s.s1[sg];
        if (act) {
            int b = task / 65, quad = task % 65;
            int c0 = quad * 4;
            float* Hb = H + (long)b * HD * HP;
            for (int row = l256; row < HD; row += 256) {
                float4 v = *(const float4*)(Hb + (long)row * HP + c0);
                s0[0][row] = v.x; s0[1][row] = v.y; s0[2][row] = v.z; s0[3][row] = v.w;
            }
        }
        __syncthreads();
        float (*src)[264] = s0, (*dst)[264] = s1p;
        int col = l256 >> 6, lane = l256 & 63;
        for (int d = 1; d < HD; d <<= 1) {   // uniform across subgroups
            for (int i = lane; i < HD; i += 64)
                dst[col][i] = src[col][i] + ((i + d < HD) ? src[col][i + d] : 0.f);
            __syncthreads();
            float (*tmp)[264] = src; src = dst; dst = tmp;
        }
        if (act) {
            int b = task / 65, quad = task % 65;
            int c0 = quad * 4;
            float* Hb = H + (long)b * HD * HP;
            for (int row = l256; row < HD; row += 256) {
                float4 v = make_float4(src[0][row], src[1][row], src[2][row], src[3][row]);
                *(float4*)(Hb + (long)row * HP + c0) = v;
            }
        }
    }
    grid.sync();

    //================ P4: assemble + matvec (2 chunks/block) + last-block finalize ================
    {
        P4S& s = *reinterpret_cast<P4S*>(smem);
        for (int c = blockIdx.x * 2; c < blockIdx.x * 2 + 2; ++c) {
            int r   = c >> 1;
            int s0c = (c & 1) * 128;
            __syncthreads();   // protect prior iteration's LDS reads
            {   // stage 128 gathered W rows: thread t -> row t>>3, float4 seg t&7
                int rr = t >> 3, u = t & 7;
                int wrow = ia[r] * 256 + ib[s0c + rr];
                *(float4*)&s.Wl[rr][u * 4] = *(const float4*)(W + (long)wrow * 32 + u * 4);
            }
            {   // stage assembled glcm chunk: thread t -> (bb = t>>7, kk = t&127)
                int bb = t >> 7, kk = t & 127;
                s.gl[bb][kk] = H[((long)bb * HD + (r + 1)) * HP + 1 + s0c + kk]
                             + GbC[((long)bb * NTH + r) * NTH + s0c + kk];
            }
            __syncthreads();
            int o = t & 31, bb = (t >> 5) & 7, q = t >> 8;
            float acc = 0.f;
#pragma unroll 8
            for (int j = 0; j < 32; ++j) {
                int kk = q * 32 + j;
                acc += s.gl[bb][kk] * s.Wl[kk][o];
            }
            s.qp[q][t & 255] = acc;
            __syncthreads();
            if (t < 256)
                partial[(long)c * 256 + t] = s.qp[0][t] + s.qp[1][t] + s.qp[2][t] + s.qp[3][t];
        }
        __threadfence();
        __syncthreads();
        if (t == 0) s.lastFlag = (atomicAdd(mvc, 1) == NBLK - 1) ? 1 : 0;
        __syncthreads();
        if (s.lastFlag) {
            __threadfence();
            int q = t >> 8, idx = t & 255;
            float sum = 0.f;
            for (int c2 = q * 128; c2 < (q + 1) * 128; ++c2)
                sum += partial[(long)c2 * 256 + idx];
            s.qp[q][idx] = sum;
            __syncthreads();
            if (t < 256)
                out[t] = fmaxf(s.qp[0][t] + s.qp[1][t] + s.qp[2][t] + s.qp[3][t] + bias[t & 31], 0.f);
        }
    }
}

extern "C" void kernel_launch(void* const* d_in, const int* in_sizes, int n_in,
                              void* d_out, int out_size, void* d_ws, size_t ws_size,
                              hipStream_t stream) {
    const float* x    = (const float*)d_in[0];
    const float* pa   = (const float*)d_in[1];
    const float* pb   = (const float*)d_in[2];
    const float* W    = (const float*)d_in[3];
    const float* bias = (const float*)d_in[4];
    float* out = (float*)d_out;
    float* ws  = (float*)d_ws;

    if (ws_size < (size_t)TOTAL_FLOATS * sizeof(float)) {
        fprintf(stderr, "kernel_launch: ws too small: %zu < %zu bytes\n",
                ws_size, (size_t)TOTAL_FLOATS * sizeof(float));
        return;
    }

    float* psa     = ws + PSA_OFF;
    int*   ia      = (int*)(ws + IA_OFF);
    float* psb     = ws + PSB_OFF;
    int*   ib      = (int*)(ws + IB_OFF);
    int*   cursor  = (int*)(ws + CUR_OFF);
    int*   mvc     = (int*)(ws + MVC_OFF);
    int*   baseA   = (int*)(ws + BASEA_OFF);
    int*   baseB   = (int*)(ws + BASEB_OFF);
    float* H       = ws + H_OFF;
    float* GbC     = ws + GBC_OFF;
    int*   bins    = (int*)(ws + BINS_OFF);
    float* partial = ws + PART_OFF;

    // zero bin cursors + completion counter (stream-ordered, graph-capturable)
    hipMemsetAsync((char*)d_ws + CUR_OFF * sizeof(float), 0,
                   (size_t)(MVC_OFF + 1 - CUR_OFF) * sizeof(float), stream);

    void* args[] = { &x, &pa, &pb, &W, &bias, &out,
                     &psa, &ia, &psb, &ib, &baseA, &baseB,
                     &cursor, &mvc, &H, &GbC, &bins, &partial };
    hipLaunchCooperativeKernel(reinterpret_cast<void*>(k_mega),
                               dim3(NBLK), dim3(1024), args, 0, stream);
}

// Round 7
// 81.790 us; speedup vs baseline: 2.9900x; 2.9900x over previous
//
#include <hip/hip_runtime.h>
#include <cstdio>
#include <cstdint>

static constexpr int  MPIX   = 51529;   // 227*227
static constexpr int  NBATCH = 8;
static constexpr int  NTH    = 256;     // number of thresholds
static constexpr int  HD     = 257;     // rank histogram dim (0..256)
static constexpr int  HP     = 260;     // padded H pitch (rows 16B-aligned)
static constexpr int  GW     = 9;       // rank-group width
static constexpr int  GRP    = 29;      // ceil(257/9) -> 8*29 = 232 tasks <= 256 CUs (no stragglers)
static constexpr int  NCH    = 51;      // pixel chunks of 1024 (51*1024 >= MPIX)
static constexpr int  CAP    = 128;     // records per (batch,group,chunk) cell (mean ~38, ~14 sd margin)

// ws layout (float slots) — d_ws is 256 MiB
static constexpr long PSA_OFF   = 0;     // 256 floats (sorted phi_a)
static constexpr long IA_OFF    = 256;   // 256 ints
static constexpr long PSB_OFF   = 512;   // 256 floats
static constexpr long IB_OFF    = 768;   // 256 ints
static constexpr long MVC_OFF   = 1024;  // 1 int (matvec completion ctr; zeroed by k_bin blk0)
static constexpr long BASEA_OFF = 1056;  // 257 ints (LUT: first idx with psa[i] >= j)
static constexpr long BASEB_OFF = 1344;  // 257 ints
static constexpr long H_OFF     = 2048;
static constexpr long H_SZ      = (long)NBATCH * HD * HP;            // 534560
static constexpr long GBC_OFF   = H_OFF + H_SZ;                      // 536608
static constexpr long GBC_SZ    = (long)NBATCH * NTH * NTH;          // 524288
static constexpr long CNTC_OFF  = GBC_OFF + GBC_SZ;                  // 1060896
static constexpr long CNTC_SZ   = (long)NBATCH * GRP * NCH;          // 11832
static constexpr long BINS_OFF  = CNTC_OFF + CNTC_SZ;                // 1072728 (even -> float2 ok)
static constexpr long BINS_SZ   = (long)NBATCH * GRP * NCH * CAP * 2;// 3028992 floats
static constexpr long PART_OFF  = BINS_OFF + BINS_SZ;                // 4101720
static constexpr long PART_SZ   = 128 * 256;                         // 32768
static constexpr long TOTAL_FLOATS = PART_OFF + PART_SZ;             // ~16.5 MB

__device__ __forceinline__ float clamp01(float v) {
    return fminf(fmaxf(v, 0.f), 1.f);
}

// LUT decode: c0 = first idx with lv[i] >= v ; c1 = first idx with lv[i] > v-1
// lbase[j] = first idx with lv[i] >= (float)j  (~unit-spaced thresholds -> ~1-step walk)
__device__ __forceinline__ void decode_lut(const float* __restrict__ lv,
                                           const int* __restrict__ lbase,
                                           float v, int& c1, int& c0) {
    if (v <= 0.f) { c1 = 0; c0 = 0; return; }
    int j = min((int)v, 255);
    int i = lbase[j];
    while (i < 256 && lv[i] < v) ++i;
    c0 = i;
    float u = v - 1.f;
    if (u < 0.f) { c1 = 0; return; }
    int j1 = min((int)u, 255);
    int i1 = lbase[j1];
    while (i1 < 256 && lv[i1] <= u) ++i1;
    c1 = i1;
}

// segmented binning: block (chunk c, batch b) sorts thresholds locally, stages its x chunk,
// writes (a,bd) records into exclusively-owned cells + per-cell counts. No global atomics.
// Block (0,0) additionally publishes sorted tables + LUTs and zeroes mvc.
__global__ void __launch_bounds__(1024)
k_bin(const float* __restrict__ x, const float* __restrict__ pa, const float* __restrict__ pb,
      int* __restrict__ cntc, float2* __restrict__ bins,
      float* __restrict__ psa, int* __restrict__ ia,
      float* __restrict__ psb, int* __restrict__ ib,
      int* __restrict__ baseA, int* __restrict__ baseB, int* __restrict__ mvc) {
    __shared__ float raw[256];
    __shared__ float la[256];
    __shared__ int   lidx[256];
    __shared__ int   cnt4[256][4];
    __shared__ int   lbaseA[257];
    __shared__ float lx[1025];
    __shared__ int   lcnt[GRP];

    int t = threadIdx.x;
    int c = blockIdx.x, b = blockIdx.y;
    int k0 = c * 1024;
    int k1 = min(k0 + 1024, MPIX);

    if (t < 256) raw[t] = pa[t];
    if (t < GRP) lcnt[t] = 0;
    {
        int k = k0 + t;
        lx[t] = (k < MPIX) ? x[(long)b * MPIX + k] : 0.f;
        if (t == 0) lx[1024] = (k0 + 1024 < MPIX) ? x[(long)b * MPIX + k0 + 1024] : 0.f;
    }
    __syncthreads();
    {   // stable rank of phi_a via 4-way split count (lane-broadcast LDS reads)
        int e = t & 255, q = t >> 8;
        float v = raw[e]; int cc = 0;
        for (int j = q * 64; j < q * 64 + 64; ++j) {
            float w = raw[j];
            cc += (w < v) || (w == v && j < e);
        }
        cnt4[e][q] = cc;
    }
    __syncthreads();
    if (t < 256) {
        int r = cnt4[t][0] + cnt4[t][1] + cnt4[t][2] + cnt4[t][3];
        la[r] = raw[t];
        lidx[r] = t;
    }
    __syncthreads();
    if (t < 257) {
        float v = (float)t;
        int lo = 0, hi = 256;
        while (lo < hi) { int m = (lo + hi) >> 1; if (la[m] < v) lo = m + 1; else hi = m; }
        lbaseA[t] = lo;
    }
    __syncthreads();

    // bin my chunk (single pass: per-cell slot via LDS atomic)
    if (k0 + t < k1) {
        float a  = lx[t];
        float bd = a - lx[t + 1];
        int ca1, ca0;
        decode_lut(la, lbaseA, a, ca1, ca0);
        int wa = min(ca0 - ca1, 127);
        int g0 = ca1 / GW;
        int g1 = min(ca1 + max(wa, 1) - 1, 256) / GW;
        float2 rec = make_float2(a, bd);
        for (int g = g0; g <= g1; ++g) {
            int slot = atomicAdd(&lcnt[g], 1);
            if (slot < CAP)
                bins[(((long)b * GRP + g) * NCH + c) * CAP + slot] = rec;
        }
    }
    __syncthreads();
    if (t < GRP) cntc[((long)b * GRP + t) * NCH + c] = min(lcnt[t], CAP);

    if (blockIdx.x == 0 && blockIdx.y == 0) {   // block-uniform: publish tables, sort B, zero mvc
        if (t < 256) { psa[t] = la[t]; ia[t] = lidx[t]; }
        if (t < 257) baseA[t] = lbaseA[t];
        if (t == 0) *mvc = 0;
        if (t < 256) raw[t] = pb[t];
        __syncthreads();
        {
            int e = t & 255, q = t >> 8;
            float v = raw[e]; int cc = 0;
            for (int j = q * 64; j < q * 64 + 64; ++j) {
                float w = raw[j];
                cc += (w < v) || (w == v && j < e);
            }
            cnt4[e][q] = cc;
        }
        __syncthreads();
        if (t < 256) {
            int r = cnt4[t][0] + cnt4[t][1] + cnt4[t][2] + cnt4[t][3];
            la[r] = raw[t];
            lidx[r] = t;
        }
        __syncthreads();
        if (t < 256) { psb[t] = la[t]; ib[t] = lidx[t]; }
        if (t < 257) {
            float v = (float)t;
            int lo = 0, hi = 256;
            while (lo < hi) { int m = (lo + hi) >> 1; if (la[m] < v) lo = m + 1; else hi = m; }
            baseB[t] = lo;
        }
    }
}

// Each block owns (batch b, 9-rank group g): reads its 51 cells (values carried in records),
// accumulates H/Ga/Gb/Csp in LDS, row-scans along cb1, flushes:
//   H[b][p][q] = rowScanH[p][q] + lGa[q-1][p-r0]   (column scan later finishes both terms)
//   GbC[b][r][s] = SufGb[r][s+1] + Csp[r][s]        (fully finished)
__global__ void __launch_bounds__(1024)
k_phase2(const float2* __restrict__ bins, const int* __restrict__ cntc,
         const float* __restrict__ psa, const float* __restrict__ psb,
         const int* __restrict__ baseA, const int* __restrict__ baseB,
         float* __restrict__ H, float* __restrict__ GbC) {
    __shared__ float la[256], lb[256];
    __shared__ int   lbA[257], lbB[257];
    __shared__ float lHG[18][257];   // rows 0..8 = H, rows 9..17 = Gb
    __shared__ float lT[18][257];
    __shared__ float lGa[256][10];   // [s][ca1-r0], padded stride 10
    __shared__ float lCsp[9][256];
    __shared__ int   cpre[NCH + 1];

    int t = threadIdx.x;
    int g = blockIdx.x, b = blockIdx.y;
    int r0 = g * GW;
    int rlen = min(GW, HD - r0);

    for (int i = t; i < 256; i += 1024) { la[i] = psa[i]; lb[i] = psb[i]; }
    for (int i = t; i < 257; i += 1024) { lbA[i] = baseA[i]; lbB[i] = baseB[i]; }
    for (int i = t; i < 18 * 257; i += 1024) (&lHG[0][0])[i] = 0.f;
    for (int i = t; i < 256 * 10; i += 1024) (&lGa[0][0])[i] = 0.f;
    for (int i = t; i < 9 * 256; i += 1024) (&lCsp[0][0])[i] = 0.f;
    if (t == 0) {
        int s = 0; cpre[0] = 0;
        const int* cb = cntc + ((long)b * GRP + g) * NCH;
        for (int c = 0; c < NCH; ++c) { s += cb[c]; cpre[c + 1] = s; }
    }
    __syncthreads();

    int total = cpre[NCH];
    const float2* binbase = bins + ((long)b * GRP + g) * NCH * CAP;
    for (int i = t; i < total; i += 1024) {
        int lo = 0, hi = NCH - 1;   // find c: cpre[c] <= i < cpre[c+1]
        while (lo < hi) { int m = (lo + hi) >> 1; if (cpre[m + 1] <= i) lo = m + 1; else hi = m; }
        int c = lo;
        float2 rec = binbase[(long)c * CAP + (i - cpre[c])];
        float a = rec.x, bd = rec.y;
        int ca1, ca0, cb1, cb0;
        decode_lut(la, lbA, a, ca1, ca0);
        decode_lut(lb, lbB, bd, cb1, cb0);
        int wa = min(ca0 - ca1, 127);
        int wb = min(cb0 - cb1, 127);
        int d = ca1 - r0;
        bool owna = (unsigned)d < (unsigned)rlen;
        int rlo = max(ca1, r0);
        int rhi = min(ca1 + wa, r0 + rlen);
        if (owna) {
            atomicAdd(&lHG[d][cb1], 1.0f);
            for (int ss = cb1; ss < cb1 + wb; ++ss)
                atomicAdd(&lGa[ss][d], clamp01(bd - lb[ss]));
        }
        for (int r = rlo; r < rhi; ++r) {
            float f = clamp01(a - la[r]);
            int rr = r - r0;
            atomicAdd(&lHG[9 + rr][cb1], f);
            for (int ss = cb1; ss < cb1 + wb; ++ss)
                atomicAdd(&lCsp[rr][ss], f * clamp01(bd - lb[ss]));
        }
    }
    __syncthreads();

    // combined suffix-scan of 18 rows along cb1 (9 passes)
    float* src = &lHG[0][0];
    float* dst = &lT[0][0];
    for (int dd = 1; dd < 257; dd <<= 1) {
        for (int i = t; i < 18 * 257; i += 1024) {
            int cc = i % 257;
            dst[i] = src[i] + ((cc + dd < 257) ? src[i + dd] : 0.f);
        }
        __syncthreads();
        float* tmp = src; src = dst; dst = tmp;
    }
    int rgb = max(0, min(rlen, NTH - r0));
    for (int rr = 0; rr < rgb; ++rr) {
        const float* gbS = src + (9 + rr) * 257;
        float* dstg = GbC + ((long)b * NTH + (r0 + rr)) * NTH;
        for (int ss = t; ss < 256; ss += 1024) dstg[ss] = gbS[ss + 1] + lCsp[rr][ss];
    }
    for (int rr = 0; rr < rlen; ++rr) {
        const float* hS = src + rr * 257;
        float* dsth = H + ((long)b * HD + (r0 + rr)) * HP;
        for (int q = t; q < 257; q += 1024)
            dsth[q] = hS[q] + ((q >= 1) ? lGa[q - 1][rr] : 0.f);
    }
}

// column suffix scans along ca1: 4 columns per block, float4 rows (HP pitch -> aligned)
__global__ void k_scanB(float* __restrict__ H) {
    __shared__ float s0[4][264], s1[4][264];
    int b = blockIdx.x / 65, grp = blockIdx.x % 65;
    int c0 = grp * 4;                          // 0..256 (cols 257..259 are pad)
    float* Hb = H + (long)b * HD * HP;
    int t = threadIdx.x;
    for (int row = t; row < HD; row += 256) {
        float4 v = *(const float4*)(Hb + (long)row * HP + c0);
        s0[0][row] = v.x; s0[1][row] = v.y; s0[2][row] = v.z; s0[3][row] = v.w;
    }
    __syncthreads();
    float (*src)[264] = s0, (*dst)[264] = s1;
    int col = t >> 6, lane = t & 63;
    for (int d = 1; d < HD; d <<= 1) {
        for (int i = lane; i < HD; i += 64)
            dst[col][i] = src[col][i] + ((i + d < HD) ? src[col][i + d] : 0.f);
        __syncthreads();
        float (*tmp)[264] = src; src = dst; dst = tmp;
    }
    for (int row = t; row < HD; row += 256) {
        float4 v = make_float4(src[0][row], src[1][row], src[2][row], src[3][row]);
        *(float4*)(Hb + (long)row * HP + c0) = v;
    }
}

// fused assemble + matvec + last-block finalize (mvc pre-zeroed by k_bin)
__global__ void k_matvec(const float* __restrict__ H, const float* __restrict__ GbC,
                         const float* __restrict__ W,
                         const int* __restrict__ ia, const int* __restrict__ ib,
                         float* __restrict__ partial, int* __restrict__ mvc,
                         const float* __restrict__ bias, float* __restrict__ out) {
    __shared__ float Wl[128][32];
    __shared__ float gl[8][128];
    __shared__ int lastFlag;
    int t = threadIdx.x;
    int bb = t >> 5, o = t & 31;
    float acc = 0.f;
#pragma unroll
    for (int it = 0; it < 4; ++it) {
        int r  = blockIdx.x * 2 + (it >> 1);   // 0..255
        int s0 = (it & 1) * 128;
        __syncthreads();
        int rr = t >> 1, half = t & 1;
        int wrow = ia[r] * 256 + ib[s0 + rr];
        const float4* srcW = reinterpret_cast<const float4*>(W + (long)wrow * 32 + half * 16);
        float4* dstW = reinterpret_cast<float4*>(&Wl[rr][half * 16]);
#pragma unroll
        for (int u = 0; u < 4; ++u) dstW[u] = srcW[u];
        {
            int bS = t >> 5, j4 = (t & 31) * 4;
            int sb = s0 + j4;
            const float4 gb = *reinterpret_cast<const float4*>(
                GbC + ((long)bS * NTH + r) * NTH + sb);
            const float* hp = H + ((long)bS * HD + (r + 1)) * HP + 1 + sb;
            float4 v;
            v.x = hp[0] + gb.x;
            v.y = hp[1] + gb.y;
            v.z = hp[2] + gb.z;
            v.w = hp[3] + gb.w;
            *reinterpret_cast<float4*>(&gl[bS][j4]) = v;
        }
        __syncthreads();
#pragma unroll 8
        for (int kk = 0; kk < 128; ++kk) acc += gl[bb][kk] * Wl[kk][o];
    }
    partial[(long)blockIdx.x * 256 + t] = acc;
    __threadfence();
    if (t == 0) lastFlag = (atomicAdd(mvc, 1) == 127) ? 1 : 0;
    __syncthreads();
    if (lastFlag) {
        __threadfence();
        float s = 0.f;
        for (int c = 0; c < 128; ++c) s += partial[(long)c * 256 + t];
        out[t] = fmaxf(s + bias[t & 31], 0.f);
    }
}

extern "C" void kernel_launch(void* const* d_in, const int* in_sizes, int n_in,
                              void* d_out, int out_size, void* d_ws, size_t ws_size,
                              hipStream_t stream) {
    const float* x    = (const float*)d_in[0];
    const float* pa   = (const float*)d_in[1];
    const float* pb   = (const float*)d_in[2];
    const float* W    = (const float*)d_in[3];
    const float* bias = (const float*)d_in[4];
    float* out = (float*)d_out;
    float* ws  = (float*)d_ws;

    if (ws_size < (size_t)TOTAL_FLOATS * sizeof(float)) {
        fprintf(stderr, "kernel_launch: ws too small: %zu < %zu bytes\n",
                ws_size, (size_t)TOTAL_FLOATS * sizeof(float));
        return;
    }

    float*  psa   = ws + PSA_OFF;
    int*    ia    = (int*)(ws + IA_OFF);
    float*  psb   = ws + PSB_OFF;
    int*    ib    = (int*)(ws + IB_OFF);
    int*    mvc   = (int*)(ws + MVC_OFF);
    int*    baseA = (int*)(ws + BASEA_OFF);
    int*    baseB = (int*)(ws + BASEB_OFF);
    float*  H     = ws + H_OFF;
    float*  GbC   = ws + GBC_OFF;
    int*    cntc  = (int*)(ws + CNTC_OFF);
    float2* bins  = (float2*)(ws + BINS_OFF);
    float*  part  = ws + PART_OFF;

    k_bin<<<dim3(NCH, NBATCH), dim3(1024), 0, stream>>>(
        x, pa, pb, cntc, bins, psa, ia, psb, ib, baseA, baseB, mvc);
    k_phase2<<<dim3(GRP, NBATCH), dim3(1024), 0, stream>>>(
        bins, cntc, psa, psb, baseA, baseB, H, GbC);
    k_scanB<<<dim3(NBATCH * 65), dim3(256), 0, stream>>>(H);
    k_matvec<<<dim3(128), dim3(256), 0, stream>>>(H, GbC, W, ia, ib, part, mvc, bias, out);
}